// Round 2
// baseline (439.960 us; speedup 1.0000x reference)
//
#include <hip/hip_runtime.h>

typedef __attribute__((ext_vector_type(8))) short bf16x8;   // 8 bf16 = 4 VGPRs
typedef __attribute__((ext_vector_type(4))) float f32x4;

__device__ __forceinline__ float bf2f(unsigned short h) {
    union { unsigned int u; float f; } v; v.u = ((unsigned int)h) << 16; return v.f;
}
__device__ __forceinline__ unsigned short f2bf(float f) {
    union { float f; unsigned int u; } v; v.f = f;
    unsigned int u = v.u;
    return (unsigned short)((u + 0x7fffu + ((u >> 16) & 1u)) >> 16);  // RNE
}

// ---------------------------------------------------------------------------
// Dtype probe: if d_in[0] is fp32, the low 16 bits of each word are random
// mantissa bits -> decoded-as-bf16 exponent is uniform over 0..255, so some
// probe word has exp >= 0x90 (P_miss ~ 0.56^256). If bf16 (x ~ N(0,1)),
// every exponent <= 0x83. flag: 1 = fp32 buffers, 0 = bf16 buffers.
// ---------------------------------------------------------------------------
__global__ void k_probe(const unsigned int* __restrict__ x, int* __restrict__ flag) {
    int lane = threadIdx.x;                     // 64 threads
    unsigned int bad = 0;
#pragma unroll
    for (int i = 0; i < 4; ++i) {
        unsigned int u = x[lane + 64 * i];
        unsigned int e = (u >> 7) & 0xFFu;      // exponent of LOW ushort as bf16
        if (e >= 0x90u) bad = 1;
    }
    unsigned long long m = __ballot(bad != 0);
    if (lane == 0) *flag = (m != 0ull) ? 1 : 0;
}

// ---------------------------------------------------------------------------
// Convert (fp32->bf16) or copy (bf16) all five inputs into the ws staging
// area: [x | w_in | b_in | w_out | b_out] in bf16, contiguous.
// ---------------------------------------------------------------------------
__global__ __launch_bounds__(256) void k_convert(const void* __restrict__ x,
        const void* __restrict__ w_in, const void* __restrict__ b_in,
        const void* __restrict__ w_out, const void* __restrict__ b_out,
        unsigned short* __restrict__ dst, const int* __restrict__ flag)
{
    const int isf = *flag;
    const long long N0 = 4194304, N1 = N0 + 3145728, N2 = N1 + 3072,
                    N3 = N2 + 1048576, N4 = N3 + 1024;
    long long stride = (long long)gridDim.x * 256;
    for (long long idx = (long long)blockIdx.x * 256 + threadIdx.x; idx < N4; idx += stride) {
        const void* src; long long off;
        if (idx < N0)      { src = x;     off = idx; }
        else if (idx < N1) { src = w_in;  off = idx - N0; }
        else if (idx < N2) { src = b_in;  off = idx - N1; }
        else if (idx < N3) { src = w_out; off = idx - N2; }
        else               { src = b_out; off = idx - N3; }
        unsigned short v = isf ? f2bf(((const float*)src)[off])
                               : ((const unsigned short*)src)[off];
        dst[idx] = v;
    }
}

// ---------------------------------------------------------------------------
// 64x64 GEMM tile core: C(64x64) = A[64 x K] * B[K x 64], bf16 in, fp32 acc.
// MFMA 16x16x32 layouts (HW-verified per guide):
//   A-frag: m = lane&15, k = (lane>>4)*8 + j
//   B-frag: n = lane&15, k = (lane>>4)*8 + j
//   C/D   : n = lane&15, m = (lane>>4)*4 + r
// ---------------------------------------------------------------------------
__device__ __forceinline__ void gemm64x64(const unsigned short* A, int lda,
                                          const unsigned short* B, int ldb, int K,
                                          unsigned short (*lA)[40], unsigned short (*lB)[40],
                                          f32x4 acc[4])
{
    const int tid = threadIdx.x;
    const int w = tid >> 6, lane = tid & 63, quad = lane >> 4, li = lane & 15;
    const int am = tid >> 2, ak = (tid & 3) * 8;
    const int bk = tid >> 3, bn = (tid & 7) * 8;
    const unsigned short* aptr = A + am * lda + ak;
    const unsigned short* bptr = B + bk * ldb + bn;
    for (int k0 = 0; k0 < K; k0 += 32) {
        uint4 av = *(const uint4*)aptr;  aptr += 32;
        uint4 bv = *(const uint4*)bptr;  bptr += 32 * ldb;
        __syncthreads();                              // previous compute done
        *(uint4*)&lA[am][ak] = av;
        union { uint4 v; unsigned short s[8]; } ub; ub.v = bv;
#pragma unroll
        for (int i = 0; i < 8; ++i) lB[bn + i][bk] = ub.s[i];   // transpose to [n][k]
        __syncthreads();
        bf16x8 af = *(const bf16x8*)&lA[w * 16 + li][quad * 8];
#pragma unroll
        for (int nt = 0; nt < 4; ++nt) {
            bf16x8 bf = *(const bf16x8*)&lB[nt * 16 + li][quad * 8];
            acc[nt] = __builtin_amdgcn_mfma_f32_16x16x32_bf16(af, bf, acc[nt], 0, 0, 0);
        }
    }
}

// ---------------------------------------------------------------------------
// QKV projection: qkv = x @ w_in + b_in; q *= 1/32 (D^-0.5).
// q_ws/k_ws: [b][h][s][64]; v transposed vt_ws: [b][h][64][s]. Grid (64,48).
// ---------------------------------------------------------------------------
__global__ __launch_bounds__(256) void k_gemm_qkv(const unsigned short* __restrict__ x,
        const unsigned short* __restrict__ w_in, const unsigned short* __restrict__ b_in,
        unsigned short* __restrict__ qws, unsigned short* __restrict__ kws,
        unsigned short* __restrict__ vtws)
{
    __shared__ unsigned short lA[64][40], lB[64][40];
    __shared__ unsigned short lC[64][72];
    const int gm0 = blockIdx.x * 64, gn0 = blockIdx.y * 64;
    f32x4 acc[4] = {{0,0,0,0},{0,0,0,0},{0,0,0,0},{0,0,0,0}};
    gemm64x64(x + gm0 * 1024, 1024, w_in + gn0, 3072, 1024, lA, lB, acc);

    const int tid = threadIdx.x, w = tid >> 6, lane = tid & 63, quad = lane >> 4, li = lane & 15;
    const float qscale = (gn0 < 1024) ? 0.03125f : 1.0f;
#pragma unroll
    for (int nt = 0; nt < 4; ++nt)
#pragma unroll
        for (int r = 0; r < 4; ++r) {
            int n = nt * 16 + li, mm = w * 16 + quad * 4 + r;
            float v = (acc[nt][r] + bf2f(b_in[gn0 + n])) * qscale;
            lC[mm][n] = f2bf(v);
        }
    __syncthreads();
    const int region = gn0 >> 10, h = (gn0 & 1023) >> 6, b = gm0 >> 10, s0 = gm0 & 1023;
    if (region < 2) {                                  // q or k: [b][h][s][d]
        unsigned short* dst = (region == 0 ? qws : kws) + ((b * 16 + h) * 1024 + s0) * 64;
        int mm = tid >> 2, c = (tid & 3) * 16;
        uint4 v0 = *(const uint4*)&lC[mm][c];
        uint4 v1 = *(const uint4*)&lC[mm][c + 8];
        *(uint4*)(dst + mm * 64 + c) = v0;
        *(uint4*)(dst + mm * 64 + c + 8) = v1;
    } else {                                           // v transposed: [b][h][d][s]
        int d = tid >> 2, c = (tid & 3) * 16;
        union { uint4 v; unsigned short s[8]; } p0, p1;
#pragma unroll
        for (int i = 0; i < 8; ++i) p0.s[i] = lC[c + i][d];
#pragma unroll
        for (int i = 0; i < 8; ++i) p1.s[i] = lC[c + 8 + i][d];
        unsigned short* dst = vtws + ((b * 16 + h) * 64 + d) * 1024 + s0 + c;
        *(uint4*)dst = p0.v;
        *(uint4*)(dst + 8) = p1.v;
    }
}

// ---------------------------------------------------------------------------
// Fused attention: block = (b, 16 q-rows), loops 16 heads. Wave w owns key
// cols [w*256, w*256+256). Exact 2-pass softmax; P -> A-layout via LDS;
// V B-frags from pre-transposed vt. attn_mean accumulated in registers.
// Output dtype of mean chosen by flag.
// ---------------------------------------------------------------------------
__global__ __launch_bounds__(256) void k_attn(const unsigned short* __restrict__ qw,
        const unsigned short* __restrict__ kw, const unsigned short* __restrict__ vtw,
        unsigned short* __restrict__ ows, void* __restrict__ dout,
        const int* __restrict__ flag)
{
    __shared__ float red[4][16];
    __shared__ float obuf[4][16][64];
    __shared__ unsigned short lp[4][16][40];
    const int b = blockIdx.y, q0 = blockIdx.x * 16;
    const int tid = threadIdx.x, w = tid >> 6, lane = tid & 63, quad = lane >> 4, li = lane & 15;
    const int isf = *flag;

    float mean_acc[64];
#pragma unroll
    for (int i = 0; i < 64; ++i) mean_acc[i] = 0.f;

    for (int h = 0; h < 16; ++h) {
        const unsigned short* qb = qw + ((b * 16 + h) * 1024 + q0 + li) * 64 + quad * 8;
        bf16x8 qf0 = *(const bf16x8*)qb;
        bf16x8 qf1 = *(const bf16x8*)(qb + 32);
        f32x4 sc[16];
        const unsigned short* kbh = kw + (b * 16 + h) * 1024 * 64;
#pragma unroll
        for (int kt = 0; kt < 16; ++kt) {
            const unsigned short* kb = kbh + (w * 256 + kt * 16 + li) * 64 + quad * 8;
            bf16x8 kf0 = *(const bf16x8*)kb;
            bf16x8 kf1 = *(const bf16x8*)(kb + 32);
            f32x4 a = {0.f, 0.f, 0.f, 0.f};
            a = __builtin_amdgcn_mfma_f32_16x16x32_bf16(qf0, kf0, a, 0, 0, 0);
            a = __builtin_amdgcn_mfma_f32_16x16x32_bf16(qf1, kf1, a, 0, 0, 0);
            sc[kt] = a;
        }
        // ---- row max (over this wave's 256 cols, then cross-wave) ----
        float rmax[4];
#pragma unroll
        for (int r = 0; r < 4; ++r) {
            float mv = sc[0][r];
#pragma unroll
            for (int kt = 1; kt < 16; ++kt) mv = fmaxf(mv, sc[kt][r]);
#pragma unroll
            for (int d = 1; d < 16; d <<= 1) mv = fmaxf(mv, __shfl_xor(mv, d, 64));
            rmax[r] = mv;
        }
        if (li == 0) {
#pragma unroll
            for (int r = 0; r < 4; ++r) red[w][quad * 4 + r] = rmax[r];
        }
        __syncthreads();
        float mrow[4];
#pragma unroll
        for (int r = 0; r < 4; ++r)
            mrow[r] = fmaxf(fmaxf(red[0][quad * 4 + r], red[1][quad * 4 + r]),
                            fmaxf(red[2][quad * 4 + r], red[3][quad * 4 + r]));
        __syncthreads();
        // ---- exp + row sum ----
        float rsum[4] = {0.f, 0.f, 0.f, 0.f};
#pragma unroll
        for (int kt = 0; kt < 16; ++kt)
#pragma unroll
            for (int r = 0; r < 4; ++r) {
                float p = __expf(sc[kt][r] - mrow[r]);
                sc[kt][r] = p;
                rsum[r] += p;
            }
#pragma unroll
        for (int r = 0; r < 4; ++r) {
            float s = rsum[r];
#pragma unroll
            for (int d = 1; d < 16; d <<= 1) s += __shfl_xor(s, d, 64);
            rsum[r] = s;
        }
        if (li == 0) {
#pragma unroll
            for (int r = 0; r < 4; ++r) red[w][quad * 4 + r] = rsum[r];
        }
        __syncthreads();
        float linv[4];
#pragma unroll
        for (int r = 0; r < 4; ++r)
            linv[r] = 1.f / (red[0][quad * 4 + r] + red[1][quad * 4 + r] +
                             red[2][quad * 4 + r] + red[3][quad * 4 + r]);
#pragma unroll
        for (int kt = 0; kt < 16; ++kt)
#pragma unroll
            for (int r = 0; r < 4; ++r) {
                float pn = sc[kt][r] * linv[r];
                sc[kt][r] = pn;
                mean_acc[kt * 4 + r] += pn;
            }
        // ---- PV: 8 chunks of 32 keys; P via LDS layout transform ----
        f32x4 oacc[4] = {{0,0,0,0},{0,0,0,0},{0,0,0,0},{0,0,0,0}};
        const unsigned short* vbh = vtw + (b * 16 + h) * 64 * 1024;
#pragma unroll
        for (int t = 0; t < 8; ++t) {
#pragma unroll
            for (int r = 0; r < 4; ++r) {
                lp[w][quad * 4 + r][li]      = f2bf(sc[2 * t][r]);
                lp[w][quad * 4 + r][16 + li] = f2bf(sc[2 * t + 1][r]);
            }
            __syncthreads();                      // uniform: all waves in same t
            bf16x8 pa = *(const bf16x8*)&lp[w][li][quad * 8];
            const int sv0 = w * 256 + t * 32;
#pragma unroll
            for (int nt = 0; nt < 4; ++nt) {
                const unsigned short* vb = vbh + (nt * 16 + li) * 1024 + sv0 + quad * 8;
                bf16x8 vf = *(const bf16x8*)vb;
                oacc[nt] = __builtin_amdgcn_mfma_f32_16x16x32_bf16(pa, vf, oacc[nt], 0, 0, 0);
            }
            __syncthreads();                      // reads done before next writes
        }
        // ---- cross-wave O reduce + write ows[b][s][h*64+d] (bf16) ----
#pragma unroll
        for (int nt = 0; nt < 4; ++nt)
#pragma unroll
            for (int r = 0; r < 4; ++r)
                obuf[w][quad * 4 + r][nt * 16 + li] = oacc[nt][r];
        __syncthreads();
        {
            int row = tid >> 4, c4 = (tid & 15) * 4;
            union { uint2 v2; unsigned short s[4]; } pk;
#pragma unroll
            for (int j = 0; j < 4; ++j) {
                float s = obuf[0][row][c4 + j] + obuf[1][row][c4 + j] +
                          obuf[2][row][c4 + j] + obuf[3][row][c4 + j];
                pk.s[j] = f2bf(s);
            }
            *(uint2*)(ows + ((b * 1024) + q0 + row) * 1024 + h * 64 + c4) = pk.v2;
        }
        __syncthreads();
    }
    // ---- write attn_mean (/16), dtype per flag ----
#pragma unroll
    for (int kt = 0; kt < 16; ++kt)
#pragma unroll
        for (int r = 0; r < 4; ++r) {
            int row = q0 + quad * 4 + r, col = w * 256 + kt * 16 + li;
            long long pos = (long long)(b * 1024 + row) * 1024 + col;
            float v = mean_acc[kt * 4 + r] * 0.0625f;
            if (isf) ((float*)dout + 4194304)[pos] = v;
            else     ((unsigned short*)dout + 4194304)[pos] = f2bf(v);
        }
}

// ---------------------------------------------------------------------------
// Output projection: out = attn_out @ w_out + b_out. Grid (64, 16).
// Output dtype per flag.
// ---------------------------------------------------------------------------
__global__ __launch_bounds__(256) void k_gemm_out(const unsigned short* __restrict__ aws,
        const unsigned short* __restrict__ w_out, const unsigned short* __restrict__ b_out,
        void* __restrict__ dout, const int* __restrict__ flag)
{
    __shared__ unsigned short lA[64][40], lB[64][40];
    __shared__ unsigned short lC[64][72];
    const int gm0 = blockIdx.x * 64, gn0 = blockIdx.y * 64;
    const int isf = *flag;
    f32x4 acc[4] = {{0,0,0,0},{0,0,0,0},{0,0,0,0},{0,0,0,0}};
    gemm64x64(aws + gm0 * 1024, 1024, w_out + gn0, 1024, 1024, lA, lB, acc);

    const int tid = threadIdx.x, w = tid >> 6, lane = tid & 63, quad = lane >> 4, li = lane & 15;
#pragma unroll
    for (int nt = 0; nt < 4; ++nt)
#pragma unroll
        for (int r = 0; r < 4; ++r) {
            int n = nt * 16 + li, mm = w * 16 + quad * 4 + r;
            lC[mm][n] = f2bf(acc[nt][r] + bf2f(b_out[gn0 + n]));
        }
    __syncthreads();
    int mm = tid >> 2, c = (tid & 3) * 16;
    if (isf) {
        float* dst = (float*)dout + (long long)(gm0 + mm) * 1024 + gn0 + c;
#pragma unroll
        for (int j4 = 0; j4 < 4; ++j4) {
            float4 f;
            f.x = bf2f(lC[mm][c + j4 * 4 + 0]);
            f.y = bf2f(lC[mm][c + j4 * 4 + 1]);
            f.z = bf2f(lC[mm][c + j4 * 4 + 2]);
            f.w = bf2f(lC[mm][c + j4 * 4 + 3]);
            *(float4*)(dst + j4 * 4) = f;
        }
    } else {
        uint4 v0 = *(const uint4*)&lC[mm][c];
        uint4 v1 = *(const uint4*)&lC[mm][c + 8];
        unsigned short* dst = (unsigned short*)dout + (gm0 + mm) * 1024 + gn0;
        *(uint4*)(dst + c) = v0;
        *(uint4*)(dst + c + 8) = v1;
    }
}

// ---------------------------------------------------------------------------
extern "C" void kernel_launch(void* const* d_in, const int* in_sizes, int n_in,
                              void* d_out, int out_size, void* d_ws, size_t ws_size,
                              hipStream_t stream)
{
    int* flag = (int*)d_ws;                                    // ws[0:4]
    unsigned short* conv = (unsigned short*)d_ws + 128;        // 256B-aligned staging
    unsigned short* xb     = conv;                             // 4,194,304
    unsigned short* w_inb  = xb + 4194304;                     // 3,145,728
    unsigned short* b_inb  = w_inb + 3145728;                  // 3,072
    unsigned short* w_outb = b_inb + 3072;                     // 1,048,576
    unsigned short* b_outb = w_outb + 1048576;                 // 1,024
    unsigned short* qws    = b_outb + 1024;                    // 4,194,304
    unsigned short* kws    = qws + 4194304;                    // 4,194,304
    unsigned short* vtws   = kws + 4194304;                    // 4,194,304
    unsigned short* ows    = xb;                               // reuse x staging (dead)

    k_probe<<<1, 64, 0, stream>>>((const unsigned int*)d_in[0], flag);
    k_convert<<<8192, 256, 0, stream>>>(d_in[0], d_in[1], d_in[2], d_in[3], d_in[4],
                                        conv, flag);
    k_gemm_qkv<<<dim3(64, 48), 256, 0, stream>>>(xb, w_inb, b_inb, qws, kws, vtws);
    k_attn   <<<dim3(64,  4), 256, 0, stream>>>(qws, kws, vtws, ows, d_out, flag);
    k_gemm_out<<<dim3(64, 16), 256, 0, stream>>>(ows, w_outb, b_outb, d_out, flag);
}